// Round 1
// baseline (607.130 us; speedup 1.0000x reference)
//
#include <hip/hip_runtime.h>
#include <stdint.h>

#define NB 4
#define NS 2048
#define NH 16
#define HSZ 64
#define ND 1024
#define NM (NB*NS)
#define NINF -10000.0f

typedef unsigned short u16;
typedef __attribute__((ext_vector_type(4))) float f32x4;
typedef __attribute__((ext_vector_type(8))) __bf16 bf16x8;

static __device__ __forceinline__ u16 f2bf(float f){
  unsigned int x = __builtin_bit_cast(unsigned int, f);
  x += 0x7fffu + ((x >> 16) & 1u);
  return (u16)(x >> 16);
}

#define GLDS16(gp, lp) __builtin_amdgcn_global_load_lds( \
    (const __attribute__((address_space(1))) void*)(gp),  \
    (__attribute__((address_space(3))) void*)(lp), 16, 0, 0)

// ---------------- cast f32 -> bf16, 4 elems/thread ----------------
__global__ __launch_bounds__(256) void k_cast(const float4* __restrict__ in,
                                              ushort4* __restrict__ out, int n4){
  int i = blockIdx.x*256 + threadIdx.x;
  if (i >= n4) return;
  float4 v = in[i];
  ushort4 o;
  o.x = f2bf(v.x); o.y = f2bf(v.y); o.z = f2bf(v.z); o.w = f2bf(v.w);
  out[i] = o;
}

// ------- transpose+cast 1024x1024: out[n][k] = bf16(in[k][n]) -------
__global__ __launch_bounds__(256) void k_transpose(const float* __restrict__ in,
                                                   u16* __restrict__ out){
  __shared__ float t[32][33];
  int tx = threadIdx.x & 31, ty = threadIdx.x >> 5;
  int n0 = blockIdx.x*32, k0 = blockIdx.y*32;
  #pragma unroll
  for (int i=0;i<32;i+=8)
    t[ty+i][tx] = in[(size_t)(k0+ty+i)*ND + n0 + tx];
  __syncthreads();
  #pragma unroll
  for (int i=0;i<32;i+=8)
    out[(size_t)(n0+ty+i)*ND + k0 + tx] = f2bf(t[tx][ty+i]);
}

// ---------------- bf16 GEMM: C[M=8192][N=1024] = A[M][K=1024] @ Bt[N][K]^T ----------------
// EPI 0: out bf16 head-split [B][H][S][64]   (Q, K)
// EPI 1: out bf16 head-split transposed [B][H][64][S]  (V^T)
// EPI 2: out f32 [M][N] = acc + bias + resid  (dense + residual)
template<int EPI>
__global__ __launch_bounds__(256,2) void k_gemm(const u16* __restrict__ A,
    const u16* __restrict__ Bt, const float* __restrict__ bias,
    const float* __restrict__ resid, void* __restrict__ Out, float scale){
  __shared__ u16 sA[128*64];
  __shared__ u16 sB[128*64];
  const int tid = threadIdx.x;
  const int wave = tid >> 6, lane = tid & 63;
  const int l15 = lane & 15, l4 = lane >> 4;
  const int m0 = blockIdx.x * 128, n0 = blockIdx.y * 128;
  const int wm = wave >> 1, wn = wave & 1;
  const f32x4 vz = {0.f,0.f,0.f,0.f};
  f32x4 acc[4][4];
  #pragma unroll
  for (int i=0;i<4;i++)
    #pragma unroll
    for (int j=0;j<4;j++) acc[i][j] = vz;

  for (int k0 = 0; k0 < 1024; k0 += 64){
    __syncthreads();
    #pragma unroll
    for (int t=0; t<4; t++){
      const int jb = (t*4 + wave)*64;
      const int j  = jb + lane;
      const int r = j >> 3, c = (j & 7) << 3;
      GLDS16(A  + (((size_t)(m0 + r)) << 10) + (size_t)(k0 + c), sA + jb*8);
      GLDS16(Bt + (((size_t)(n0 + r)) << 10) + (size_t)(k0 + c), sB + jb*8);
    }
    __syncthreads();
    #pragma unroll
    for (int kk=0; kk<64; kk+=32){
      bf16x8 af[4], bv[4];
      #pragma unroll
      for (int mi=0;mi<4;mi++)
        af[mi] = *(const bf16x8*)(const void*)(sA + (wm*64 + mi*16 + l15)*64 + kk + l4*8);
      #pragma unroll
      for (int ni=0;ni<4;ni++)
        bv[ni] = *(const bf16x8*)(const void*)(sB + (wn*64 + ni*16 + l15)*64 + kk + l4*8);
      #pragma unroll
      for (int mi=0;mi<4;mi++)
        #pragma unroll
        for (int ni=0;ni<4;ni++)
          acc[mi][ni] = __builtin_amdgcn_mfma_f32_16x16x32_bf16(af[mi], bv[ni], acc[mi][ni], 0, 0, 0);
    }
  }

  #pragma unroll
  for (int mi=0;mi<4;mi++){
    #pragma unroll
    for (int ni=0;ni<4;ni++){
      const int n = n0 + wn*64 + ni*16 + l15;
      const float bvv = bias[n];
      #pragma unroll
      for (int j=0;j<4;j++){
        const int m = m0 + wm*64 + mi*16 + l4*4 + j;
        float v = (acc[mi][ni][j] + bvv) * scale;
        if (EPI == 0){
          const int b = m >> 11, s = m & (NS-1), h = n >> 6, d = n & 63;
          ((u16*)Out)[((((size_t)b*NH + h)*NS + s) << 6) + d] = f2bf(v);
        } else if (EPI == 1){
          const int b = m >> 11, s = m & (NS-1), h = n >> 6, d = n & 63;
          ((u16*)Out)[((((size_t)b*NH + h)*HSZ + d) << 11) + s] = f2bf(v);
        } else {
          const size_t o = ((size_t)m << 10) + n;
          ((float*)Out)[o] = v + resid[o];
        }
      }
    }
  }
}

// ---------------- attention pass 1: per-row (max, 1/sumexp) stats ----------------
__global__ __launch_bounds__(256,2) void k_attn_stats(const u16* __restrict__ Q,
    const u16* __restrict__ K, const int* __restrict__ mask,
    float2* __restrict__ stats){
  __shared__ u16 sK[64][80];
  const int tid = threadIdx.x, wave = tid>>6, lane = tid&63;
  const int l15 = lane&15, l4 = lane>>4;
  const int qb = blockIdx.x, h = blockIdx.y, b = blockIdx.z;
  const int bh = b*NH + h;
  const size_t hoff = (size_t)bh * NS * HSZ;
  const int q0 = qb*64 + wave*16;
  const bf16x8 qf0 = *(const bf16x8*)(const void*)(Q + hoff + (size_t)(q0+l15)*HSZ + l4*8);
  const bf16x8 qf1 = *(const bf16x8*)(const void*)(Q + hoff + (size_t)(q0+l15)*HSZ + 32 + l4*8);
  const f32x4 vz = {0.f,0.f,0.f,0.f};
  float mr[4] = {-1e30f,-1e30f,-1e30f,-1e30f};
  float lr[4] = {0.f,0.f,0.f,0.f};
  for (int kb=0; kb<NS; kb+=64){
    __syncthreads();
    #pragma unroll
    for (int t=0;t<2;t++){
      int j = t*256 + tid;
      int r = j>>3, c = (j&7)<<3;
      *(int4*)(void*)&sK[r][c] = *(const int4*)(const void*)(K + hoff + (size_t)(kb+r)*HSZ + c);
    }
    __syncthreads();
    float sc[4][4];
    #pragma unroll
    for (int n=0;n<4;n++){
      bf16x8 kf0 = *(const bf16x8*)(const void*)&sK[n*16+l15][l4*8];
      bf16x8 kf1 = *(const bf16x8*)(const void*)&sK[n*16+l15][32+l4*8];
      f32x4 a = vz;
      a = __builtin_amdgcn_mfma_f32_16x16x32_bf16(qf0, kf0, a, 0,0,0);
      a = __builtin_amdgcn_mfma_f32_16x16x32_bf16(qf1, kf1, a, 0,0,0);
      const int key = kb + n*16 + l15;
      const float madd = mask[b*NS + key] ? NINF : 0.f;
      #pragma unroll
      for (int j=0;j<4;j++) sc[n][j] = a[j] + madd;
    }
    #pragma unroll
    for (int j=0;j<4;j++){
      float tm = fmaxf(fmaxf(sc[0][j],sc[1][j]), fmaxf(sc[2][j],sc[3][j]));
      float mn = fmaxf(mr[j], tm);
      float sum = __expf(sc[0][j]-mn) + __expf(sc[1][j]-mn)
                + __expf(sc[2][j]-mn) + __expf(sc[3][j]-mn);
      lr[j] = lr[j]*__expf(mr[j]-mn) + sum;
      mr[j] = mn;
    }
  }
  #pragma unroll
  for (int j=0;j<4;j++){
    float m = mr[j], l = lr[j];
    #pragma unroll
    for (int off=1; off<16; off<<=1){
      float mo = __shfl_xor(m, off, 64);
      float lo = __shfl_xor(l, off, 64);
      float mn = fmaxf(m, mo);
      l = l*__expf(m-mn) + lo*__expf(mo-mn);
      m = mn;
    }
    if (l15 == 0)
      stats[(size_t)bh*NS + q0 + l4*4 + j] = make_float2(m, 1.f/l);
  }
}

// --------- attention pass 2: recompute scores, write attn f32, ctx = P@V ---------
__global__ __launch_bounds__(256,2) void k_attn_pv(const u16* __restrict__ Q,
    const u16* __restrict__ K, const u16* __restrict__ Vt,
    const int* __restrict__ mask, const float2* __restrict__ stats,
    float* __restrict__ attn, u16* __restrict__ ctx){
  __shared__ u16 sK[64][80];
  __shared__ u16 sV[64][80];
  __shared__ u16 sP[4][16][80];
  const int tid = threadIdx.x, wave = tid>>6, lane = tid&63;
  const int l15 = lane&15, l4 = lane>>4;
  const int qb = blockIdx.x, h = blockIdx.y, b = blockIdx.z;
  const int bh = b*NH + h;
  const size_t hoff = (size_t)bh * NS * HSZ;
  const int q0 = qb*64 + wave*16;
  const bf16x8 qf0 = *(const bf16x8*)(const void*)(Q + hoff + (size_t)(q0+l15)*HSZ + l4*8);
  const bf16x8 qf1 = *(const bf16x8*)(const void*)(Q + hoff + (size_t)(q0+l15)*HSZ + 32 + l4*8);
  float mrow[4], rinv[4];
  #pragma unroll
  for (int j=0;j<4;j++){
    float2 st = stats[(size_t)bh*NS + q0 + l4*4 + j];
    mrow[j] = st.x; rinv[j] = st.y;
  }
  const f32x4 vz = {0.f,0.f,0.f,0.f};
  f32x4 cacc[4];
  #pragma unroll
  for (int i=0;i<4;i++) cacc[i] = vz;
  float* attn_base = attn + (size_t)bh * NS * NS;

  for (int kb=0; kb<NS; kb+=64){
    __syncthreads();
    #pragma unroll
    for (int t=0;t<2;t++){
      int j = t*256 + tid;
      int r = j>>3, c = (j&7)<<3;
      *(int4*)(void*)&sK[r][c] = *(const int4*)(const void*)(K  + hoff + (size_t)(kb+r)*HSZ + c);
      *(int4*)(void*)&sV[r][c] = *(const int4*)(const void*)(Vt + hoff + (size_t)r*NS + kb + c);
    }
    __syncthreads();
    #pragma unroll
    for (int n=0;n<4;n++){
      bf16x8 kf0 = *(const bf16x8*)(const void*)&sK[n*16+l15][l4*8];
      bf16x8 kf1 = *(const bf16x8*)(const void*)&sK[n*16+l15][32+l4*8];
      f32x4 a = vz;
      a = __builtin_amdgcn_mfma_f32_16x16x32_bf16(qf0, kf0, a, 0,0,0);
      a = __builtin_amdgcn_mfma_f32_16x16x32_bf16(qf1, kf1, a, 0,0,0);
      const int key = kb + n*16 + l15;
      const float madd = mask[b*NS + key] ? NINF : 0.f;
      #pragma unroll
      for (int j=0;j<4;j++){
        float p = __expf(a[j] + madd - mrow[j]) * rinv[j];
        attn_base[(size_t)(q0 + l4*4 + j)*NS + key] = p;
        sP[wave][l4*4+j][n*16+l15] = f2bf(p);
      }
    }
    #pragma unroll
    for (int kk=0;kk<2;kk++){
      bf16x8 pf = *(const bf16x8*)(const void*)&sP[wave][l15][kk*32 + l4*8];
      #pragma unroll
      for (int n2=0;n2<4;n2++){
        bf16x8 vf = *(const bf16x8*)(const void*)&sV[n2*16+l15][kk*32 + l4*8];
        cacc[n2] = __builtin_amdgcn_mfma_f32_16x16x32_bf16(pf, vf, cacc[n2], 0,0,0);
      }
    }
  }
  #pragma unroll
  for (int n2=0;n2<4;n2++)
    #pragma unroll
    for (int j=0;j<4;j++){
      const int q = q0 + l4*4 + j;
      ctx[(((size_t)(b*NS + q)) << 10) + h*HSZ + n2*16 + l15] = f2bf(cacc[n2][j]);
    }
}

// ---------------- in-place LayerNorm over rows of 1024 ----------------
__global__ __launch_bounds__(256) void k_layernorm(float* __restrict__ buf,
    const float* __restrict__ gamma, const float* __restrict__ beta){
  const int row = blockIdx.x, tid = threadIdx.x;
  float4* rp = (float4*)(buf + ((size_t)row << 10));
  float4 a = rp[tid];
  float s  = a.x + a.y + a.z + a.w;
  float ss = a.x*a.x + a.y*a.y + a.z*a.z + a.w*a.w;
  #pragma unroll
  for (int off=1; off<64; off<<=1){
    s  += __shfl_xor(s,  off, 64);
    ss += __shfl_xor(ss, off, 64);
  }
  __shared__ float red[8];
  const int wave = tid>>6, lane = tid&63;
  if (lane == 0){ red[wave] = s; red[wave+4] = ss; }
  __syncthreads();
  s  = red[0]+red[1]+red[2]+red[3];
  ss = red[4]+red[5]+red[6]+red[7];
  const float mu  = s * (1.f/1024.f);
  const float var = ss * (1.f/1024.f) - mu*mu;
  const float rs  = rsqrtf(var + 1e-6f);
  float4 g  = ((const float4*)gamma)[tid];
  float4 be = ((const float4*)beta)[tid];
  float4 o;
  o.x = (a.x-mu)*rs*g.x + be.x;
  o.y = (a.y-mu)*rs*g.y + be.y;
  o.z = (a.z-mu)*rs*g.z + be.z;
  o.w = (a.w-mu)*rs*g.w + be.w;
  rp[tid] = o;
}

extern "C" void kernel_launch(void* const* d_in, const int* in_sizes, int n_in,
                              void* d_out, int out_size, void* d_ws, size_t ws_size,
                              hipStream_t stream){
  const float* x     = (const float*)d_in[0];
  const int*   mask  = (const int*)d_in[1];
  const float* wq_w  = (const float*)d_in[2];
  const float* wq_b  = (const float*)d_in[3];
  const float* wk_w  = (const float*)d_in[4];
  const float* wk_b  = (const float*)d_in[5];
  const float* wv_w  = (const float*)d_in[6];
  const float* wv_b  = (const float*)d_in[7];
  const float* wd_w  = (const float*)d_in[8];
  const float* wd_b  = (const float*)d_in[9];
  const float* gamma = (const float*)d_in[10];
  const float* beta  = (const float*)d_in[11];

  float* out0 = (float*)d_out;                    // [8192][1024] f32
  float* attn = out0 + (size_t)NM * ND;           // [4][16][2048][2048] f32

  char* ws = (char*)d_ws;
  u16*    xb    = (u16*)(ws);                     // 16 MB  (aliased by ctx later)
  u16*    ctx   = (u16*)(ws);                     // alias: xb dead after QKV GEMMs
  u16*    wqt   = (u16*)(ws + 16777216);          // 2 MB each
  u16*    wkt   = (u16*)(ws + 18874368);
  u16*    wvt   = (u16*)(ws + 20971520);
  u16*    wdt   = (u16*)(ws + 23068672);
  u16*    Qb    = (u16*)(ws + 25165824);          // 16 MB
  u16*    Kb    = (u16*)(ws + 41943040);          // 16 MB
  u16*    Vtb   = (u16*)(ws + 58720256);          // 16 MB
  float2* stats = (float2*)(ws + 75497472);       // 1 MB  -> total ~73 MB

  k_cast<<<8192, 256, 0, stream>>>((const float4*)x, (ushort4*)xb, NM*ND/4);
  dim3 tg(32, 32);
  k_transpose<<<tg, 256, 0, stream>>>(wq_w, wqt);
  k_transpose<<<tg, 256, 0, stream>>>(wk_w, wkt);
  k_transpose<<<tg, 256, 0, stream>>>(wv_w, wvt);
  k_transpose<<<tg, 256, 0, stream>>>(wd_w, wdt);

  dim3 gg(64, 8);
  k_gemm<0><<<gg, 256, 0, stream>>>(xb, wqt, wq_b, nullptr, Qb, 0.125f); // Q pre-scaled 1/sqrt(64)
  k_gemm<0><<<gg, 256, 0, stream>>>(xb, wkt, wk_b, nullptr, Kb, 1.0f);
  k_gemm<1><<<gg, 256, 0, stream>>>(xb, wvt, wv_b, nullptr, Vtb, 1.0f);  // V^T layout

  dim3 ag(NS/64, NH, NB);
  k_attn_stats<<<ag, 256, 0, stream>>>(Qb, Kb, mask, stats);
  k_attn_pv<<<ag, 256, 0, stream>>>(Qb, Kb, Vtb, mask, stats, attn, ctx);

  k_gemm<2><<<gg, 256, 0, stream>>>(ctx, wdt, wd_b, x, out0, 1.0f);      // + bias + residual
  k_layernorm<<<NM, 256, 0, stream>>>(out0, gamma, beta);
}

// Round 2
// 544.161 us; speedup vs baseline: 1.1157x; 1.1157x over previous
//
#include <hip/hip_runtime.h>
#include <stdint.h>

#define NB 4
#define NS 2048
#define NH 16
#define HSZ 64
#define ND 1024
#define NM (NB*NS)
// exp(x) = exp2(x*log2e); fold 1/sqrt(64)*log2e into Q scale
#define QSCALE 0.180336880f

typedef unsigned short u16;
typedef __attribute__((ext_vector_type(4))) float f32x4;
typedef __attribute__((ext_vector_type(8))) __bf16 bf16x8;

static __device__ __forceinline__ u16 f2bf(float f){
  unsigned int x = __builtin_bit_cast(unsigned int, f);
  x += 0x7fffu + ((x >> 16) & 1u);
  return (u16)(x >> 16);
}

#define GLDS16(gp, lp) __builtin_amdgcn_global_load_lds( \
    (const __attribute__((address_space(1))) void*)(gp),  \
    (__attribute__((address_space(3))) void*)(lp), 16, 0, 0)

// ---------------- cast f32 -> bf16, 4 elems/thread ----------------
__global__ __launch_bounds__(256) void k_cast(const float4* __restrict__ in,
                                              ushort4* __restrict__ out, int n4){
  int i = blockIdx.x*256 + threadIdx.x;
  if (i >= n4) return;
  float4 v = in[i];
  ushort4 o;
  o.x = f2bf(v.x); o.y = f2bf(v.y); o.z = f2bf(v.z); o.w = f2bf(v.w);
  out[i] = o;
}

// --- transpose+cast 1024x1024 x4: wq,wk,wv -> wcat (concat), wd -> wdt ---
__global__ __launch_bounds__(256) void k_transpose4(const float* __restrict__ wq,
    const float* __restrict__ wk, const float* __restrict__ wv,
    const float* __restrict__ wd, u16* __restrict__ wcat, u16* __restrict__ wdt){
  __shared__ float t[32][33];
  const int z = blockIdx.z;
  const float* in = (z==0) ? wq : (z==1) ? wk : (z==2) ? wv : wd;
  u16* out = (z<3) ? (wcat + (size_t)z*ND*ND) : wdt;
  int tx = threadIdx.x & 31, ty = threadIdx.x >> 5;
  int n0 = blockIdx.x*32, k0 = blockIdx.y*32;
  #pragma unroll
  for (int i=0;i<32;i+=8)
    t[ty+i][tx] = in[(size_t)(k0+ty+i)*ND + n0 + tx];
  __syncthreads();
  #pragma unroll
  for (int i=0;i<32;i+=8)
    out[(size_t)(n0+ty+i)*ND + k0 + tx] = f2bf(t[tx][ty+i]);
}

// ---------------- bf16 GEMM core: C[M=8192][N] = A[M][1024] @ Bt[N][1024]^T ----------------
// EPI 0: fused QKV (N=3072): sec 0 -> Q bf16 [B][H][S][64] scaled by QSCALE;
//        sec 1 -> K bf16 same layout; sec 2 -> V^T bf16 [B][H][64][S]
// EPI 2: dense (N=1024): out f32 [M][N] = acc + bias + resid
template<int EPI>
__global__ __launch_bounds__(256,2) void k_gemm(const u16* __restrict__ A,
    const u16* __restrict__ Bt, const float* __restrict__ b0,
    const float* __restrict__ b1, const float* __restrict__ b2,
    const float* __restrict__ resid, u16* __restrict__ Qo, u16* __restrict__ Ko,
    u16* __restrict__ Vto, float* __restrict__ Out){
  __shared__ u16 sA[128*64];
  __shared__ u16 sB[128*64];
  const int tid = threadIdx.x;
  const int wave = tid >> 6, lane = tid & 63;
  const int l15 = lane & 15, l4 = lane >> 4;
  const int m0 = blockIdx.x * 128, n0 = blockIdx.y * 128;
  const int wm = wave >> 1, wn = wave & 1;
  const f32x4 vz = {0.f,0.f,0.f,0.f};
  f32x4 acc[4][4];
  #pragma unroll
  for (int i=0;i<4;i++)
    #pragma unroll
    for (int j=0;j<4;j++) acc[i][j] = vz;

  for (int k0 = 0; k0 < 1024; k0 += 64){
    __syncthreads();
    #pragma unroll
    for (int t=0; t<4; t++){
      const int jb = (t*4 + wave)*64;
      const int j  = jb + lane;
      const int r = j >> 3, c = (j & 7) << 3;
      GLDS16(A  + (((size_t)(m0 + r)) << 10) + (size_t)(k0 + c), sA + jb*8);
      GLDS16(Bt + (((size_t)(n0 + r)) << 10) + (size_t)(k0 + c), sB + jb*8);
    }
    __syncthreads();
    #pragma unroll
    for (int kk=0; kk<64; kk+=32){
      bf16x8 af[4], bv[4];
      #pragma unroll
      for (int mi=0;mi<4;mi++)
        af[mi] = *(const bf16x8*)(const void*)(sA + (wm*64 + mi*16 + l15)*64 + kk + l4*8);
      #pragma unroll
      for (int ni=0;ni<4;ni++)
        bv[ni] = *(const bf16x8*)(const void*)(sB + (wn*64 + ni*16 + l15)*64 + kk + l4*8);
      #pragma unroll
      for (int mi=0;mi<4;mi++)
        #pragma unroll
        for (int ni=0;ni<4;ni++)
          acc[mi][ni] = __builtin_amdgcn_mfma_f32_16x16x32_bf16(af[mi], bv[ni], acc[mi][ni], 0, 0, 0);
    }
  }

  if (EPI == 0){
    const int sec = n0 >> 10;                       // block-uniform
    const float* bias = (sec==0) ? b0 : (sec==1) ? b1 : b2;
    const float scale = (sec==0) ? QSCALE : 1.0f;
    u16* dst = (sec==0) ? Qo : (sec==1) ? Ko : Vto;
    #pragma unroll
    for (int mi=0;mi<4;mi++){
      #pragma unroll
      for (int ni=0;ni<4;ni++){
        const int n = n0 + wn*64 + ni*16 + l15;
        const int nn = n & (ND-1);
        const int h = nn >> 6, d = nn & 63;
        const float bvv = bias[nn];
        #pragma unroll
        for (int j=0;j<4;j++){
          const int m = m0 + wm*64 + mi*16 + l4*4 + j;
          const int b = m >> 11, s = m & (NS-1);
          const float v = (acc[mi][ni][j] + bvv) * scale;
          if (sec < 2)
            dst[((((size_t)b*NH + h)*NS + s) << 6) + d] = f2bf(v);
          else
            dst[((((size_t)b*NH + h)*HSZ + d) << 11) + s] = f2bf(v);
        }
      }
    }
  } else {
    #pragma unroll
    for (int mi=0;mi<4;mi++){
      #pragma unroll
      for (int ni=0;ni<4;ni++){
        const int n = n0 + wn*64 + ni*16 + l15;
        const float bvv = b0[n];
        #pragma unroll
        for (int j=0;j<4;j++){
          const int m = m0 + wm*64 + mi*16 + l4*4 + j;
          const size_t o = ((size_t)m << 10) + n;
          Out[o] = acc[mi][ni][j] + bvv + resid[o];
        }
      }
    }
  }
}

// ------- attention pass 1: per-row 1/sum(exp2(s')) (fixed max = 0) -------
__global__ __launch_bounds__(256,4) void k_attn_stats(const u16* __restrict__ Q,
    const u16* __restrict__ K, const int* __restrict__ mask,
    float* __restrict__ stats){
  __shared__ u16 sK[64][72];
  const int tid = threadIdx.x, wave = tid>>6, lane = tid&63;
  const int l15 = lane&15, l4 = lane>>4;
  const int qb = blockIdx.x, h = blockIdx.y, b = blockIdx.z;
  const int bh = b*NH + h;
  const size_t hoff = (size_t)bh * NS * HSZ;
  const int q0 = qb*64 + wave*16;
  const bf16x8 qf0 = *(const bf16x8*)(const void*)(Q + hoff + (size_t)(q0+l15)*HSZ + l4*8);
  const bf16x8 qf1 = *(const bf16x8*)(const void*)(Q + hoff + (size_t)(q0+l15)*HSZ + 32 + l4*8);
  const f32x4 vz = {0.f,0.f,0.f,0.f};
  float lr[4] = {0.f,0.f,0.f,0.f};
  for (int kb=0; kb<NS; kb+=64){
    __syncthreads();
    #pragma unroll
    for (int t=0;t<2;t++){
      int j = t*256 + tid;
      int r = j>>3, c = (j&7)<<3;
      *(int4*)(void*)&sK[r][c] = *(const int4*)(const void*)(K + hoff + (size_t)(kb+r)*HSZ + c);
    }
    __syncthreads();
    #pragma unroll
    for (int n=0;n<4;n++){
      bf16x8 kf0 = *(const bf16x8*)(const void*)&sK[n*16+l15][l4*8];
      bf16x8 kf1 = *(const bf16x8*)(const void*)&sK[n*16+l15][32+l4*8];
      f32x4 a = vz;
      a = __builtin_amdgcn_mfma_f32_16x16x32_bf16(qf0, kf0, a, 0,0,0);
      a = __builtin_amdgcn_mfma_f32_16x16x32_bf16(qf1, kf1, a, 0,0,0);
      const int key = kb + n*16 + l15;
      const bool msk = mask[b*NS + key] != 0;
      #pragma unroll
      for (int j=0;j<4;j++)
        lr[j] += msk ? 0.f : __builtin_amdgcn_exp2f(a[j]);
    }
  }
  #pragma unroll
  for (int j=0;j<4;j++){
    float l = lr[j];
    #pragma unroll
    for (int off=1; off<16; off<<=1)
      l += __shfl_xor(l, off, 64);
    if (l15 == 0)
      stats[(size_t)bh*NS + q0 + l4*4 + j] = 1.f/l;
  }
}

// --------- attention pass 2: recompute scores, write attn f32, ctx = P@V ---------
__global__ __launch_bounds__(256,4) void k_attn_pv(const u16* __restrict__ Q,
    const u16* __restrict__ K, const u16* __restrict__ Vt,
    const int* __restrict__ mask, const float* __restrict__ stats,
    float* __restrict__ attn, u16* __restrict__ ctx){
  __shared__ u16 sK[64][72];
  __shared__ u16 sV[64][72];
  __shared__ u16 sP[4][16][72];
  const int tid = threadIdx.x, wave = tid>>6, lane = tid&63;
  const int l15 = lane&15, l4 = lane>>4;
  const int qb = blockIdx.x, h = blockIdx.y, b = blockIdx.z;
  const int bh = b*NH + h;
  const size_t hoff = (size_t)bh * NS * HSZ;
  const int q0 = qb*64 + wave*16;
  const bf16x8 qf0 = *(const bf16x8*)(const void*)(Q + hoff + (size_t)(q0+l15)*HSZ + l4*8);
  const bf16x8 qf1 = *(const bf16x8*)(const void*)(Q + hoff + (size_t)(q0+l15)*HSZ + 32 + l4*8);
  float rinv[4];
  #pragma unroll
  for (int j=0;j<4;j++)
    rinv[j] = stats[(size_t)bh*NS + q0 + l4*4 + j];
  const f32x4 vz = {0.f,0.f,0.f,0.f};
  f32x4 cacc[4];
  #pragma unroll
  for (int i=0;i<4;i++) cacc[i] = vz;
  float* attn_base = attn + (size_t)bh * NS * NS;

  for (int kb=0; kb<NS; kb+=64){
    __syncthreads();
    #pragma unroll
    for (int t=0;t<2;t++){
      int j = t*256 + tid;
      int r = j>>3, c = (j&7)<<3;
      *(int4*)(void*)&sK[r][c] = *(const int4*)(const void*)(K  + hoff + (size_t)(kb+r)*HSZ + c);
      *(int4*)(void*)&sV[r][c] = *(const int4*)(const void*)(Vt + hoff + (size_t)r*NS + kb + c);
    }
    __syncthreads();
    #pragma unroll
    for (int n=0;n<4;n++){
      bf16x8 kf0 = *(const bf16x8*)(const void*)&sK[n*16+l15][l4*8];
      bf16x8 kf1 = *(const bf16x8*)(const void*)&sK[n*16+l15][32+l4*8];
      f32x4 a = vz;
      a = __builtin_amdgcn_mfma_f32_16x16x32_bf16(qf0, kf0, a, 0,0,0);
      a = __builtin_amdgcn_mfma_f32_16x16x32_bf16(qf1, kf1, a, 0,0,0);
      const int key = kb + n*16 + l15;
      const bool msk = mask[b*NS + key] != 0;
      #pragma unroll
      for (int j=0;j<4;j++){
        const float e = msk ? 0.f : __builtin_amdgcn_exp2f(a[j]);
        const float p = e * rinv[j];
        attn_base[(size_t)(q0 + l4*4 + j)*NS + key] = p;
        sP[wave][l4*4+j][n*16+l15] = f2bf(p);
      }
    }
    #pragma unroll
    for (int kk=0;kk<2;kk++){
      bf16x8 pf = *(const bf16x8*)(const void*)&sP[wave][l15][kk*32 + l4*8];
      #pragma unroll
      for (int n2=0;n2<4;n2++){
        bf16x8 vf = *(const bf16x8*)(const void*)&sV[n2*16+l15][kk*32 + l4*8];
        cacc[n2] = __builtin_amdgcn_mfma_f32_16x16x32_bf16(pf, vf, cacc[n2], 0,0,0);
      }
    }
  }
  #pragma unroll
  for (int n2=0;n2<4;n2++)
    #pragma unroll
    for (int j=0;j<4;j++){
      const int q = q0 + l4*4 + j;
      ctx[(((size_t)(b*NS + q)) << 10) + h*HSZ + n2*16 + l15] = f2bf(cacc[n2][j]);
    }
}

// ---------------- in-place LayerNorm over rows of 1024 ----------------
__global__ __launch_bounds__(256) void k_layernorm(float* __restrict__ buf,
    const float* __restrict__ gamma, const float* __restrict__ beta){
  const int row = blockIdx.x, tid = threadIdx.x;
  float4* rp = (float4*)(buf + ((size_t)row << 10));
  float4 a = rp[tid];
  float s  = a.x + a.y + a.z + a.w;
  float ss = a.x*a.x + a.y*a.y + a.z*a.z + a.w*a.w;
  #pragma unroll
  for (int off=1; off<64; off<<=1){
    s  += __shfl_xor(s,  off, 64);
    ss += __shfl_xor(ss, off, 64);
  }
  __shared__ float red[8];
  const int wave = tid>>6, lane = tid&63;
  if (lane == 0){ red[wave] = s; red[wave+4] = ss; }
  __syncthreads();
  s  = red[0]+red[1]+red[2]+red[3];
  ss = red[4]+red[5]+red[6]+red[7];
  const float mu  = s * (1.f/1024.f);
  const float var = ss * (1.f/1024.f) - mu*mu;
  const float rs  = rsqrtf(var + 1e-6f);
  float4 g  = ((const float4*)gamma)[tid];
  float4 be = ((const float4*)beta)[tid];
  float4 o;
  o.x = (a.x-mu)*rs*g.x + be.x;
  o.y = (a.y-mu)*rs*g.y + be.y;
  o.z = (a.z-mu)*rs*g.z + be.z;
  o.w = (a.w-mu)*rs*g.w + be.w;
  rp[tid] = o;
}

extern "C" void kernel_launch(void* const* d_in, const int* in_sizes, int n_in,
                              void* d_out, int out_size, void* d_ws, size_t ws_size,
                              hipStream_t stream){
  const float* x     = (const float*)d_in[0];
  const int*   mask  = (const int*)d_in[1];
  const float* wq_w  = (const float*)d_in[2];
  const float* wq_b  = (const float*)d_in[3];
  const float* wk_w  = (const float*)d_in[4];
  const float* wk_b  = (const float*)d_in[5];
  const float* wv_w  = (const float*)d_in[6];
  const float* wv_b  = (const float*)d_in[7];
  const float* wd_w  = (const float*)d_in[8];
  const float* wd_b  = (const float*)d_in[9];
  const float* gamma = (const float*)d_in[10];
  const float* beta  = (const float*)d_in[11];

  float* out0 = (float*)d_out;                    // [8192][1024] f32
  float* attn = out0 + (size_t)NM * ND;           // [4][16][2048][2048] f32

  char* ws = (char*)d_ws;
  u16*   xb    = (u16*)(ws);                      // 16 MB (aliased by ctx later)
  u16*   ctx   = (u16*)(ws);                      // alias: xb dead after QKV GEMM
  u16*   wcat  = (u16*)(ws + (16u<<20));          // 6 MB: wq^T|wk^T|wv^T
  u16*   wdt   = (u16*)(ws + (22u<<20));          // 2 MB
  u16*   Qb    = (u16*)(ws + (24u<<20));          // 16 MB
  u16*   Kb    = (u16*)(ws + (40u<<20));          // 16 MB
  u16*   Vtb   = (u16*)(ws + (56u<<20));          // 16 MB
  float* stats = (float*)(ws + (72u<<20));        // 0.5 MB -> total 72.5 MB

  k_cast<<<8192, 256, 0, stream>>>((const float4*)x, (ushort4*)xb, NM*ND/4);
  k_transpose4<<<dim3(32,32,4), 256, 0, stream>>>(wq_w, wk_w, wv_w, wd_w, wcat, wdt);

  // fused QKV: C[8192][3072]
  k_gemm<0><<<dim3(64,24), 256, 0, stream>>>(xb, wcat, wq_b, wk_b, wv_b,
                                             nullptr, Qb, Kb, Vtb, nullptr);

  dim3 ag(NS/64, NH, NB);
  k_attn_stats<<<ag, 256, 0, stream>>>(Qb, Kb, mask, stats);
  k_attn_pv<<<ag, 256, 0, stream>>>(Qb, Kb, Vtb, mask, stats, attn, ctx);

  k_gemm<2><<<dim3(64,8), 256, 0, stream>>>(ctx, wdt, wd_b, nullptr, nullptr,
                                            x, nullptr, nullptr, nullptr, out0);
  k_layernorm<<<NM, 256, 0, stream>>>(out0, gamma, beta);
}